// Round 2
// baseline (366.328 us; speedup 1.0000x reference)
//
#include <hip/hip_runtime.h>
#include <math.h>

#define N_NODES 20000
#define N_EDGES 320000
#define EMB 128
#define HID 512          // 4*EMB
#define PQ_STRIDE 1024   // P (512) + Q (512) per node

// ---------------------------------------------------------------------------
// float atomic max via int/uint monotone bit trick (init must be -inf)
// ---------------------------------------------------------------------------
__device__ __forceinline__ void atomicMaxFloat(float* addr, float v) {
    if (v >= 0.0f) {
        atomicMax((int*)addr, __float_as_int(v));
    } else {
        atomicMin((unsigned int*)addr, __float_as_uint(v));
    }
}

// ---------------------------------------------------------------------------
// init: node reduction buffers + degree histogram counters
// ---------------------------------------------------------------------------
__global__ void init_nodes(float* __restrict__ node_max, float* __restrict__ node_sum,
                           int* __restrict__ deg) {
    int i = blockIdx.x * 256 + threadIdx.x;
    if (i < N_NODES) {
        node_max[i] = -INFINITY;
        node_sum[i] = 0.0f;
        deg[i] = 0;
    }
}

__global__ void histogram_rows(const int* __restrict__ row, int* __restrict__ deg) {
    int e = blockIdx.x * 256 + threadIdx.x;
    if (e < N_EDGES) atomicAdd(&deg[row[e]], 1);
}

// ---------------------------------------------------------------------------
// exclusive prefix sum over deg -> cursor (single block, wave-shuffle scan)
// ---------------------------------------------------------------------------
__device__ __forceinline__ int wave_incl_scan(int v, int lane) {
#pragma unroll
    for (int off = 1; off < 64; off <<= 1) {
        int t = __shfl_up(v, off, 64);
        if (lane >= off) v += t;
    }
    return v;
}

__global__ __launch_bounds__(1024) void scan_offsets(const int* __restrict__ deg,
                                                     int* __restrict__ cursor) {
    __shared__ int wsum[16];
    __shared__ int chunk_total;
    __shared__ int carry_s;
    const int tid = threadIdx.x, lane = tid & 63, w = tid >> 6;
    if (tid == 0) carry_s = 0;
    __syncthreads();
    for (int base = 0; base < N_NODES; base += 1024) {
        int i = base + tid;
        int v = (i < N_NODES) ? deg[i] : 0;
        int incl = wave_incl_scan(v, lane);
        if (lane == 63) wsum[w] = incl;
        __syncthreads();
        if (w == 0) {
            int x = (lane < 16) ? wsum[lane] : 0;
            int xs = wave_incl_scan(x, lane);
            if (lane == 15) chunk_total = xs;
            if (lane < 16) wsum[lane] = xs - x;   // exclusive wave offsets
        }
        __syncthreads();
        int excl = carry_s + wsum[w] + incl - v;
        if (i < N_NODES) cursor[i] = excl;
        __syncthreads();                           // all carry_s reads done
        if (tid == 0) carry_s += chunk_total;
        __syncthreads();
    }
}

// ---------------------------------------------------------------------------
// scatter edges into row-sorted order (order within a bucket is arbitrary)
// ---------------------------------------------------------------------------
__global__ void scatter_edges(const int* __restrict__ row, const int* __restrict__ col,
                              int* __restrict__ cursor, int* __restrict__ perm,
                              int* __restrict__ row_s, int* __restrict__ col_s) {
    int e = blockIdx.x * 256 + threadIdx.x;
    if (e >= N_EDGES) return;
    int r = row[e];
    int pos = atomicAdd(&cursor[r], 1);
    perm[pos] = e;
    row_s[pos] = r;
    col_s[pos] = col[e];
}

// ---------------------------------------------------------------------------
// GEMM: PQ[n, 0:512]   = h @ W1[0:128, :]    (P)
//       PQ[n, 512:1024]= h @ W1[128:256, :]  (Q)
// M=20000, K=128, N=1024. f32 vector ALU (no fp32 MFMA on CDNA4).
// 128x64 tile, BK=16, 256 threads, 8x4 micro-tile (32 FMA per 3 ds_read_b128).
// ---------------------------------------------------------------------------
#define TM 128
#define TN 64
#define BK 16

__global__ __launch_bounds__(256) void gemm_pq(
    const float* __restrict__ h, const float* __restrict__ W1,
    float* __restrict__ PQ)
{
    __shared__ float As[BK][TM + 4];   // +4: keep float4 alignment, break bank stride
    __shared__ float Bs[BK][TN];

    const int tid = threadIdx.x;
    const int nt  = blockIdx.x;           // 0..15  (column tile of 64 over 1024)
    const int mt  = blockIdx.y;           // 0..156 (row tile of 128 over 20000)
    const int m_base = mt * TM;

    // staging: A is 128 rows x 16 k = 2048 floats = 512 float4 -> 2 per thread
    const int a_m = tid >> 1;             // 0..127
    const int a_k = (tid & 1) << 3;       // 0 or 8 (two consecutive float4s)
    // B: 16 x 64 = 1024 floats = 256 float4 -> 1 per thread
    const int b_k = tid >> 4;             // 0..15
    const int b_n = (tid & 15) << 2;      // 0..60

    // compute: 16x16 thread grid, each 8 rows x 4 cols
    const int ty = tid >> 4;              // 0..15
    const int tx = tid & 15;              // 0..15
    const int cm = ty << 3;               // row offset in tile
    const int cn = tx << 2;               // col offset in tile

    float acc[8][4] = {};

    const int  row_a = m_base + a_m;
    const bool a_ok  = row_a < N_NODES;

    const int w_row_off = (nt < 8) ? 0 : 128;   // P half vs Q half of W1
    const int w_col     = ((nt & 7) << 6) + b_n;

    for (int k0 = 0; k0 < EMB; k0 += BK) {
        float4 av0 = make_float4(0.f, 0.f, 0.f, 0.f);
        float4 av1 = make_float4(0.f, 0.f, 0.f, 0.f);
        if (a_ok) {
            av0 = *(const float4*)(h + (size_t)row_a * EMB + k0 + a_k);
            av1 = *(const float4*)(h + (size_t)row_a * EMB + k0 + a_k + 4);
        }
        As[a_k + 0][a_m] = av0.x;
        As[a_k + 1][a_m] = av0.y;
        As[a_k + 2][a_m] = av0.z;
        As[a_k + 3][a_m] = av0.w;
        As[a_k + 4][a_m] = av1.x;
        As[a_k + 5][a_m] = av1.y;
        As[a_k + 6][a_m] = av1.z;
        As[a_k + 7][a_m] = av1.w;

        float4 bv = *(const float4*)(W1 + (size_t)(w_row_off + k0 + b_k) * HID + w_col);
        *(float4*)&Bs[b_k][b_n] = bv;

        __syncthreads();
#pragma unroll
        for (int kk = 0; kk < BK; ++kk) {
            float a[8], b[4];
            *(float4*)&a[0] = *(const float4*)&As[kk][cm];
            *(float4*)&a[4] = *(const float4*)&As[kk][cm + 4];
            *(float4*)&b[0] = *(const float4*)&Bs[kk][cn];
#pragma unroll
            for (int i = 0; i < 8; ++i)
#pragma unroll
                for (int j = 0; j < 4; ++j)
                    acc[i][j] = fmaf(a[i], b[j], acc[i][j]);
        }
        __syncthreads();
    }

    const int col_base = nt * TN + cn;
#pragma unroll
    for (int i = 0; i < 8; ++i) {
        int r = m_base + cm + i;
        if (r < N_NODES) {
            *(float4*)(PQ + (size_t)r * PQ_STRIDE + col_base) =
                make_float4(acc[i][0], acc[i][1], acc[i][2], acc[i][3]);
        }
    }
}

// ---------------------------------------------------------------------------
// One wave per SORTED edge: consecutive waves share the same row -> P row
// loads hit L1/L2. score = sum_j relu(P[r,j]+Q[c,j]+b1[j])*W2[j] + b2.
// Writes score back to original edge slot via perm; segment-max via atomics.
// ---------------------------------------------------------------------------
__global__ __launch_bounds__(256) void edge_scores(
    const float* __restrict__ PQ, const float* __restrict__ b1,
    const float* __restrict__ W2, const float* __restrict__ b2,
    const int* __restrict__ row_s, const int* __restrict__ col_s,
    const int* __restrict__ perm,
    float* __restrict__ scores, float* __restrict__ node_max)
{
    const int i    = (blockIdx.x << 2) + (threadIdx.x >> 6);  // sorted index
    const int lane = threadIdx.x & 63;
    if (i >= N_EDGES) return;

    const int r = row_s[i];
    const int c = col_s[i];
    const float* __restrict__ p = PQ + (size_t)r * PQ_STRIDE;        // P half
    const float* __restrict__ q = PQ + (size_t)c * PQ_STRIDE + HID;  // Q half
    const int j0 = lane << 2;

    float4 p0 = *(const float4*)(p + j0);
    float4 p1 = *(const float4*)(p + 256 + j0);
    float4 q0 = *(const float4*)(q + j0);
    float4 q1 = *(const float4*)(q + 256 + j0);
    float4 bb0 = *(const float4*)(b1 + j0);
    float4 bb1 = *(const float4*)(b1 + 256 + j0);
    float4 w0 = *(const float4*)(W2 + j0);
    float4 w1 = *(const float4*)(W2 + 256 + j0);

    float s = 0.0f;
    s = fmaf(fmaxf(p0.x + q0.x + bb0.x, 0.0f), w0.x, s);
    s = fmaf(fmaxf(p0.y + q0.y + bb0.y, 0.0f), w0.y, s);
    s = fmaf(fmaxf(p0.z + q0.z + bb0.z, 0.0f), w0.z, s);
    s = fmaf(fmaxf(p0.w + q0.w + bb0.w, 0.0f), w0.w, s);
    s = fmaf(fmaxf(p1.x + q1.x + bb1.x, 0.0f), w1.x, s);
    s = fmaf(fmaxf(p1.y + q1.y + bb1.y, 0.0f), w1.y, s);
    s = fmaf(fmaxf(p1.z + q1.z + bb1.z, 0.0f), w1.z, s);
    s = fmaf(fmaxf(p1.w + q1.w + bb1.w, 0.0f), w1.w, s);

#pragma unroll
    for (int off = 32; off > 0; off >>= 1)
        s += __shfl_down(s, off, 64);

    if (lane == 0) {
        float sc = s + b2[0];
        scores[perm[i]] = sc;
        atomicMaxFloat(&node_max[r], sc);
    }
}

// ---------------------------------------------------------------------------
// exp(score - segmax) + segment sum
// ---------------------------------------------------------------------------
__global__ void edge_expsum(
    const float* __restrict__ scores, const int* __restrict__ row,
    const float* __restrict__ node_max, float* __restrict__ e_val,
    float* __restrict__ node_sum)
{
    int e = blockIdx.x * 256 + threadIdx.x;
    if (e >= N_EDGES) return;
    int r = row[e];
    float ev = expf(scores[e] - node_max[r]);
    e_val[e] = ev;
    atomicAdd(&node_sum[r], ev);
}

// ---------------------------------------------------------------------------
// probs -> relaxed bernoulli -> straight-through hard mask -> outputs
// IEEE inf semantics required (probs==1 -> logits=+inf -> y=1); no fast-math.
// ---------------------------------------------------------------------------
__global__ void finalize(
    const float* __restrict__ scores, const float* __restrict__ e_val,
    const float* __restrict__ node_sum, const int* __restrict__ row,
    const float* __restrict__ u, const int* __restrict__ edge_mask,
    const int* __restrict__ hierarchy,
    float* __restrict__ out_y, float* __restrict__ out_mask,
    float* __restrict__ out_causal, float* __restrict__ out_spu)
{
    int e = blockIdx.x * 256 + threadIdx.x;
    if (e >= N_EDGES) return;
    int r = row[e];
    float p = e_val[e] / node_sum[r];
    float logits = logf(p) - log1pf(-p);        // +inf when p==1 (single-edge segment)
    float uu = u[e];
    float L = logf(uu) - log1pf(-uu);
    float t = logits + L;
    float y = 1.0f / (1.0f + expf(-t));         // t=+inf -> 1, t=-inf -> 0
    bool hard = y > 0.5f;                       // y_st forward value is exactly y_hard
    int hv = hierarchy[0];
    int m = hard ? (hv + 1) : edge_mask[e];
    float sc = scores[e];
    out_y[e]      = hard ? 1.0f : 0.0f;
    out_mask[e]   = (float)m;
    out_causal[e] = (m > 0)   ?  sc : 0.0f;
    out_spu[e]    = (m == -1) ? -sc : 0.0f;
}

// ---------------------------------------------------------------------------
extern "C" void kernel_launch(void* const* d_in, const int* in_sizes, int n_in,
                              void* d_out, int out_size, void* d_ws, size_t ws_size,
                              hipStream_t stream) {
    const float* h_ptr = (const float*)d_in[0];
    const float* W1    = (const float*)d_in[1];
    const float* b1    = (const float*)d_in[2];
    const float* W2    = (const float*)d_in[3];
    const float* b2    = (const float*)d_in[4];
    const float* u     = (const float*)d_in[5];
    const int*   row   = (const int*)d_in[6];
    const int*   col   = (const int*)d_in[7];
    const int*   emask = (const int*)d_in[8];
    const int*   hier  = (const int*)d_in[9];

    float* out        = (float*)d_out;
    float* scores     = out;                        // [E]
    float* out_y      = out + (size_t)N_EDGES;      // [E]
    float* out_mask   = out + 2 * (size_t)N_EDGES;  // [E]
    float* out_causal = out + 3 * (size_t)N_EDGES;  // [E]
    float* out_spu    = out + 4 * (size_t)N_EDGES;  // [E]

    // workspace layout (4B units):
    // node_max[20000] node_sum[20000] deg[20000] cursor[20000]
    // perm[320000] row_s[320000] col_s[320000] e_val[320000] PQ[20000*1024]
    float* node_max = (float*)d_ws;
    float* node_sum = node_max + N_NODES;
    int*   deg      = (int*)(node_sum + N_NODES);
    int*   cursor   = deg + N_NODES;
    int*   perm     = cursor + N_NODES;
    int*   row_s    = perm + N_EDGES;
    int*   col_s    = row_s + N_EDGES;
    float* e_val    = (float*)(col_s + N_EDGES);
    float* PQ       = e_val + N_EDGES;

    hipLaunchKernelGGL(init_nodes, dim3((N_NODES + 255) / 256), dim3(256), 0, stream,
                       node_max, node_sum, deg);

    hipLaunchKernelGGL(histogram_rows, dim3((N_EDGES + 255) / 256), dim3(256), 0, stream,
                       row, deg);

    hipLaunchKernelGGL(scan_offsets, dim3(1), dim3(1024), 0, stream, deg, cursor);

    hipLaunchKernelGGL(scatter_edges, dim3((N_EDGES + 255) / 256), dim3(256), 0, stream,
                       row, col, cursor, perm, row_s, col_s);

    dim3 ggrid(PQ_STRIDE / TN, (N_NODES + TM - 1) / TM);  // 16 x 157
    hipLaunchKernelGGL(gemm_pq, ggrid, dim3(256), 0, stream, h_ptr, W1, PQ);

    hipLaunchKernelGGL(edge_scores, dim3(N_EDGES / 4), dim3(256), 0, stream,
                       PQ, b1, W2, b2, row_s, col_s, perm, scores, node_max);

    hipLaunchKernelGGL(edge_expsum, dim3((N_EDGES + 255) / 256), dim3(256), 0, stream,
                       scores, row, node_max, e_val, node_sum);

    hipLaunchKernelGGL(finalize, dim3((N_EDGES + 255) / 256), dim3(256), 0, stream,
                       scores, e_val, node_sum, row, u, emask, hier,
                       out_y, out_mask, out_causal, out_spu);
}

// Round 3
// 327.258 us; speedup vs baseline: 1.1194x; 1.1194x over previous
//
#include <hip/hip_runtime.h>
#include <math.h>

#define N_NODES 20000
#define N_EDGES 320000
#define EMB 128
#define HID 512          // 4*EMB
#define PQ_STRIDE 1024   // P (512) + Q (512) per node
#define ROWS_PER_BLOCK 16
#define SC_CAP 2048      // LDS score cache per block (spill path for pathological skew)

// ---------------------------------------------------------------------------
// init: zero degree histogram; set offs[N_NODES] = N_EDGES sentinel
// ---------------------------------------------------------------------------
__global__ void init_deg(int* __restrict__ deg, int* __restrict__ offs) {
    int i = blockIdx.x * 256 + threadIdx.x;
    if (i < N_NODES) deg[i] = 0;
    if (i == 0) offs[N_NODES] = N_EDGES;
}

__global__ void histogram_rows(const int* __restrict__ row, int* __restrict__ deg) {
    int e = blockIdx.x * 256 + threadIdx.x;
    if (e < N_EDGES) atomicAdd(&deg[row[e]], 1);
}

// ---------------------------------------------------------------------------
// exclusive prefix sum over deg -> cursor + offs (single block, shuffle scan)
// ---------------------------------------------------------------------------
__device__ __forceinline__ int wave_incl_scan(int v, int lane) {
#pragma unroll
    for (int off = 1; off < 64; off <<= 1) {
        int t = __shfl_up(v, off, 64);
        if (lane >= off) v += t;
    }
    return v;
}

__global__ __launch_bounds__(1024) void scan_offsets(const int* __restrict__ deg,
                                                     int* __restrict__ cursor,
                                                     int* __restrict__ offs) {
    __shared__ int wsum[16];
    __shared__ int chunk_total;
    __shared__ int carry_s;
    const int tid = threadIdx.x, lane = tid & 63, w = tid >> 6;
    if (tid == 0) carry_s = 0;
    __syncthreads();
    for (int base = 0; base < N_NODES; base += 1024) {
        int i = base + tid;
        int v = (i < N_NODES) ? deg[i] : 0;
        int incl = wave_incl_scan(v, lane);
        if (lane == 63) wsum[w] = incl;
        __syncthreads();
        if (w == 0) {
            int x = (lane < 16) ? wsum[lane] : 0;
            int xs = wave_incl_scan(x, lane);
            if (lane == 15) chunk_total = xs;
            if (lane < 16) wsum[lane] = xs - x;   // exclusive wave offsets
        }
        __syncthreads();
        int excl = carry_s + wsum[w] + incl - v;
        if (i < N_NODES) { cursor[i] = excl; offs[i] = excl; }
        __syncthreads();                           // all carry_s reads done
        if (tid == 0) carry_s += chunk_total;
        __syncthreads();
    }
}

// ---------------------------------------------------------------------------
// scatter edges into row-sorted order (order within a bucket is arbitrary)
// ---------------------------------------------------------------------------
__global__ void scatter_edges(const int* __restrict__ row, const int* __restrict__ col,
                              int* __restrict__ cursor, int* __restrict__ perm,
                              int* __restrict__ col_s) {
    int e = blockIdx.x * 256 + threadIdx.x;
    if (e >= N_EDGES) return;
    int r = row[e];
    int pos = atomicAdd(&cursor[r], 1);
    perm[pos] = e;
    col_s[pos] = col[e];
}

// ---------------------------------------------------------------------------
// GEMM: PQ[n, 0:512] = h @ W1[0:128,:], PQ[n, 512:1024] = h @ W1[128:256,:]
// M=20000, N=1024, K=128, f32 vector ALU. 128x128 tile, BK=16, 256 threads,
// 8x8 micro-tile split {cn, cn+64} (2-way LDS aliasing = free), register
// prefetch of tile t+1 before compute of tile t.
// ---------------------------------------------------------------------------
#define TM 128
#define TN 128
#define BK 16
#define NTILES (EMB / BK)   // 8

__global__ __launch_bounds__(256) void gemm_pq(
    const float* __restrict__ h, const float* __restrict__ W1,
    float* __restrict__ PQ)
{
    __shared__ float As[BK][TM + 4];   // transposed A tile, stride 132
    __shared__ float Bs[BK][TN];

    const int tid = threadIdx.x;
    const int nt  = blockIdx.x;           // 0..7: col tile of 128 over 1024
    const int mt  = blockIdx.y;           // 0..156
    const int m_base = mt * TM;

    // A staging: 128 rows x 16 k = 512 float4 -> 2 consecutive f4 per thread
    const int a_m = tid >> 1;             // 0..127
    const int a_k = (tid & 1) << 3;       // 0 or 8
    const int  row_a = m_base + a_m;
    const bool a_ok  = row_a < N_NODES;
    const float* __restrict__ hrow = h + (size_t)row_a * EMB + a_k;

    // B staging: 16 rows x 128 cols = 512 float4 -> 2 per thread (col, col+64)
    const int b_k = tid >> 4;             // 0..15
    const int b_n = (tid & 15) << 2;      // 0..60
    const int w_row_off = (nt < 4) ? 0 : 128;       // P half vs Q half of W1
    const int w_col     = (nt & 3) * TN + b_n;
    const float* __restrict__ wrow = W1 + (size_t)(w_row_off + b_k) * HID + w_col;

    // compute mapping: 16x16 threads, rows {cm..cm+3, cm+64..}, cols {cn.., cn+64..}
    const int ty = tid >> 4, tx = tid & 15;
    const int cm = ty << 2, cn = tx << 2;

    float acc[8][8] = {};   // [i<4: row cm+i | i>=4: cm+64+i-4][j<4: cn+j | j>=4: cn+64+j-4]

    float4 pa0, pa1, pb0, pb1;
    // prefetch tile 0
    {
        pa0 = make_float4(0.f,0.f,0.f,0.f); pa1 = pa0;
        if (a_ok) { pa0 = *(const float4*)(hrow); pa1 = *(const float4*)(hrow + 4); }
        pb0 = *(const float4*)(wrow);
        pb1 = *(const float4*)(wrow + 64);
    }

    for (int t = 0; t < NTILES; ++t) {
        // stage registers -> LDS
        As[a_k + 0][a_m] = pa0.x;
        As[a_k + 1][a_m] = pa0.y;
        As[a_k + 2][a_m] = pa0.z;
        As[a_k + 3][a_m] = pa0.w;
        As[a_k + 4][a_m] = pa1.x;
        As[a_k + 5][a_m] = pa1.y;
        As[a_k + 6][a_m] = pa1.z;
        As[a_k + 7][a_m] = pa1.w;
        *(float4*)&Bs[b_k][b_n]      = pb0;
        *(float4*)&Bs[b_k][b_n + 64] = pb1;
        __syncthreads();

        // prefetch tile t+1 (global loads in flight across the compute below)
        if (t + 1 < NTILES) {
            const int k0 = (t + 1) * BK;
            pa0 = make_float4(0.f,0.f,0.f,0.f); pa1 = pa0;
            if (a_ok) { pa0 = *(const float4*)(hrow + k0); pa1 = *(const float4*)(hrow + k0 + 4); }
            pb0 = *(const float4*)(wrow + (size_t)k0 * HID);
            pb1 = *(const float4*)(wrow + (size_t)k0 * HID + 64);
        }

#pragma unroll
        for (int kk = 0; kk < BK; ++kk) {
            float a[8], b[8];
            *(float4*)&a[0] = *(const float4*)&As[kk][cm];
            *(float4*)&a[4] = *(const float4*)&As[kk][cm + 64];
            *(float4*)&b[0] = *(const float4*)&Bs[kk][cn];
            *(float4*)&b[4] = *(const float4*)&Bs[kk][cn + 64];
#pragma unroll
            for (int i = 0; i < 8; ++i)
#pragma unroll
                for (int j = 0; j < 8; ++j)
                    acc[i][j] = fmaf(a[i], b[j], acc[i][j]);
        }
        __syncthreads();
    }

    const int col_base = nt * TN;
#pragma unroll
    for (int i = 0; i < 8; ++i) {
        const int r = m_base + cm + (i < 4 ? i : 64 + i - 4);
        if (r < N_NODES) {
            float* dst = PQ + (size_t)r * PQ_STRIDE + col_base;
            *(float4*)(dst + cn)      = make_float4(acc[i][0], acc[i][1], acc[i][2], acc[i][3]);
            *(float4*)(dst + cn + 64) = make_float4(acc[i][4], acc[i][5], acc[i][6], acc[i][7]);
        }
    }
}

// ---------------------------------------------------------------------------
// Fused edge phase: block owns ROWS_PER_BLOCK consecutive rows = complete
// softmax segments (edges contiguous in sorted order).
// Phase 1: wave-per-edge MLP scores -> LDS (+ global scores output).
// Phase 2: wave-per-row segment softmax + relaxed bernoulli + outputs.
// No atomics, no extra passes over global memory.
// ---------------------------------------------------------------------------
__global__ __launch_bounds__(256) void fused_edge(
    const float* __restrict__ PQ, const float* __restrict__ b1,
    const float* __restrict__ W2, const float* __restrict__ b2,
    const int* __restrict__ col_s, const int* __restrict__ perm,
    const int* __restrict__ offs,
    const float* __restrict__ u, const int* __restrict__ edge_mask,
    const int* __restrict__ hierarchy,
    float* __restrict__ scores, float* __restrict__ out_y,
    float* __restrict__ out_mask, float* __restrict__ out_causal,
    float* __restrict__ out_spu)
{
    __shared__ float sc_lds[SC_CAP];

    const int r0 = blockIdx.x * ROWS_PER_BLOCK;
    const int r1 = (r0 + ROWS_PER_BLOCK < N_NODES) ? r0 + ROWS_PER_BLOCK : N_NODES;
    const int e0 = offs[r0];
    const int e1 = offs[r1];
    const int tid = threadIdx.x, lane = tid & 63, w = tid >> 6;
    const int j0 = lane << 2;

    // ---- phase 1: scores (one wave per edge) ----
    for (int i = e0 + w; i < e1; i += 4) {
        const int c = col_s[i];
        // row for edge i: P row. Rows in [r0,r1); find via offs? Not needed:
        // P pointer requires the row id. Recover it cheaply: since segments are
        // contiguous we could search, but loading it is simpler — store row in
        // high bits? We kept col only; derive row by linear scan over <=16 rows.
        int r = r0;
        while (offs[r + 1] <= i) ++r;   // <=16 iterations, wave-uniform
        const float* __restrict__ p = PQ + (size_t)r * PQ_STRIDE;
        const float* __restrict__ q = PQ + (size_t)c * PQ_STRIDE + HID;

        float4 p0 = *(const float4*)(p + j0);
        float4 p1 = *(const float4*)(p + 256 + j0);
        float4 q0 = *(const float4*)(q + j0);
        float4 q1 = *(const float4*)(q + 256 + j0);
        float4 bb0 = *(const float4*)(b1 + j0);
        float4 bb1 = *(const float4*)(b1 + 256 + j0);
        float4 w0 = *(const float4*)(W2 + j0);
        float4 w1 = *(const float4*)(W2 + 256 + j0);

        float s = 0.0f;
        s = fmaf(fmaxf(p0.x + q0.x + bb0.x, 0.0f), w0.x, s);
        s = fmaf(fmaxf(p0.y + q0.y + bb0.y, 0.0f), w0.y, s);
        s = fmaf(fmaxf(p0.z + q0.z + bb0.z, 0.0f), w0.z, s);
        s = fmaf(fmaxf(p0.w + q0.w + bb0.w, 0.0f), w0.w, s);
        s = fmaf(fmaxf(p1.x + q1.x + bb1.x, 0.0f), w1.x, s);
        s = fmaf(fmaxf(p1.y + q1.y + bb1.y, 0.0f), w1.y, s);
        s = fmaf(fmaxf(p1.z + q1.z + bb1.z, 0.0f), w1.z, s);
        s = fmaf(fmaxf(p1.w + q1.w + bb1.w, 0.0f), w1.w, s);

#pragma unroll
        for (int off = 32; off > 0; off >>= 1)
            s += __shfl_down(s, off, 64);

        if (lane == 0) {
            float sc = s + b2[0];
            scores[perm[i]] = sc;
            int li = i - e0;
            if (li < SC_CAP) sc_lds[li] = sc;
        }
    }
    __syncthreads();

    // ---- phase 2: wave per row ----
    const int hv = hierarchy[0];
    for (int r = r0 + w; r < r1; r += 4) {
        const int es = offs[r], ee = offs[r + 1];
        const int d = ee - es;
        if (d == 0) continue;

        float m = -INFINITY;
        for (int j = lane; j < d; j += 64) {
            int li = es - e0 + j;
            float s = (li < SC_CAP) ? sc_lds[li] : scores[perm[es + j]];
            m = fmaxf(m, s);
        }
#pragma unroll
        for (int off = 32; off > 0; off >>= 1)
            m = fmaxf(m, __shfl_down(m, off, 64));
        m = __shfl(m, 0, 64);

        float ssum = 0.0f;
        for (int j = lane; j < d; j += 64) {
            int li = es - e0 + j;
            float s = (li < SC_CAP) ? sc_lds[li] : scores[perm[es + j]];
            ssum += expf(s - m);
        }
#pragma unroll
        for (int off = 32; off > 0; off >>= 1)
            ssum += __shfl_down(ssum, off, 64);
        ssum = __shfl(ssum, 0, 64);

        for (int j = lane; j < d; j += 64) {
            int li = es - e0 + j;
            float s = (li < SC_CAP) ? sc_lds[li] : scores[perm[es + j]];
            float p = expf(s - m) / ssum;
            float logits = logf(p) - log1pf(-p);   // +inf when p==1 (d==1)
            int oe = perm[es + j];
            float uu = u[oe];
            float L = logf(uu) - log1pf(-uu);
            float y = 1.0f / (1.0f + expf(-(logits + L)));
            bool hard = y > 0.5f;                  // ST forward value == y_hard
            int mm = hard ? (hv + 1) : edge_mask[oe];
            out_y[oe]      = hard ? 1.0f : 0.0f;
            out_mask[oe]   = (float)mm;
            out_causal[oe] = (mm > 0)   ?  s : 0.0f;
            out_spu[oe]    = (mm == -1) ? -s : 0.0f;
        }
    }
}

// ---------------------------------------------------------------------------
extern "C" void kernel_launch(void* const* d_in, const int* in_sizes, int n_in,
                              void* d_out, int out_size, void* d_ws, size_t ws_size,
                              hipStream_t stream) {
    const float* h_ptr = (const float*)d_in[0];
    const float* W1    = (const float*)d_in[1];
    const float* b1    = (const float*)d_in[2];
    const float* W2    = (const float*)d_in[3];
    const float* b2    = (const float*)d_in[4];
    const float* u     = (const float*)d_in[5];
    const int*   row   = (const int*)d_in[6];
    const int*   col   = (const int*)d_in[7];
    const int*   emask = (const int*)d_in[8];
    const int*   hier  = (const int*)d_in[9];

    float* out        = (float*)d_out;
    float* scores     = out;                        // [E]
    float* out_y      = out + (size_t)N_EDGES;      // [E]
    float* out_mask   = out + 2 * (size_t)N_EDGES;  // [E]
    float* out_causal = out + 3 * (size_t)N_EDGES;  // [E]
    float* out_spu    = out + 4 * (size_t)N_EDGES;  // [E]

    // workspace layout (4B units), PQ first for 16B alignment:
    // PQ[20000*1024] deg[20000] cursor[20000] offs[20001] perm[E] col_s[E]
    float* PQ     = (float*)d_ws;
    int*   deg    = (int*)(PQ + (size_t)N_NODES * PQ_STRIDE);
    int*   cursor = deg + N_NODES;
    int*   offs   = cursor + N_NODES;
    int*   perm   = offs + N_NODES + 1;
    int*   col_s  = perm + N_EDGES;

    hipLaunchKernelGGL(init_deg, dim3((N_NODES + 255) / 256), dim3(256), 0, stream,
                       deg, offs);

    hipLaunchKernelGGL(histogram_rows, dim3((N_EDGES + 255) / 256), dim3(256), 0, stream,
                       row, deg);

    hipLaunchKernelGGL(scan_offsets, dim3(1), dim3(1024), 0, stream, deg, cursor, offs);

    hipLaunchKernelGGL(scatter_edges, dim3((N_EDGES + 255) / 256), dim3(256), 0, stream,
                       row, col, cursor, perm, col_s);

    dim3 ggrid(PQ_STRIDE / TN, (N_NODES + TM - 1) / TM);  // 8 x 157
    hipLaunchKernelGGL(gemm_pq, ggrid, dim3(256), 0, stream, h_ptr, W1, PQ);

    hipLaunchKernelGGL(fused_edge, dim3((N_NODES + ROWS_PER_BLOCK - 1) / ROWS_PER_BLOCK),
                       dim3(256), 0, stream,
                       PQ, b1, W2, b2, col_s, perm, offs, u, emask, hier,
                       scores, out_y, out_mask, out_causal, out_spu);
}

// Round 4
// 323.474 us; speedup vs baseline: 1.1325x; 1.0117x over previous
//
#include <hip/hip_runtime.h>
#include <math.h>

#define N_NODES 20000
#define N_EDGES 320000
#define EMB 128
#define HID 512          // 4*EMB
#define PQ_STRIDE 1024   // P (512, bias-folded) + Q (512) per node
#define ROWS_PER_BLOCK 16
#define SC_CAP 2048      // LDS score cache per block (spill path never hit in practice)

typedef float v2f __attribute__((ext_vector_type(2)));

#if defined(__has_builtin)
#if __has_builtin(__builtin_elementwise_fma)
#define V2FMA(a, b, c) __builtin_elementwise_fma((a), (b), (c))
#else
#define V2FMA(a, b, c) ((a) * (b) + (c))
#endif
#else
#define V2FMA(a, b, c) ((a) * (b) + (c))
#endif

// ---------------------------------------------------------------------------
// init: zero degree histogram; set offs[N_NODES] = N_EDGES sentinel
// ---------------------------------------------------------------------------
__global__ void init_deg(int* __restrict__ deg, int* __restrict__ offs) {
    int i = blockIdx.x * 256 + threadIdx.x;
    if (i < N_NODES) deg[i] = 0;
    if (i == 0) offs[N_NODES] = N_EDGES;
}

__global__ void histogram_rows(const int* __restrict__ row, int* __restrict__ deg) {
    int e = blockIdx.x * 256 + threadIdx.x;
    if (e < N_EDGES) atomicAdd(&deg[row[e]], 1);
}

// ---------------------------------------------------------------------------
// exclusive prefix sum over deg -> cursor + offs (single block, shuffle scan)
// ---------------------------------------------------------------------------
__device__ __forceinline__ int wave_incl_scan(int v, int lane) {
#pragma unroll
    for (int off = 1; off < 64; off <<= 1) {
        int t = __shfl_up(v, off, 64);
        if (lane >= off) v += t;
    }
    return v;
}

__global__ __launch_bounds__(1024) void scan_offsets(const int* __restrict__ deg,
                                                     int* __restrict__ cursor,
                                                     int* __restrict__ offs) {
    __shared__ int wsum[16];
    __shared__ int chunk_total;
    __shared__ int carry_s;
    const int tid = threadIdx.x, lane = tid & 63, w = tid >> 6;
    if (tid == 0) carry_s = 0;
    __syncthreads();
    for (int base = 0; base < N_NODES; base += 1024) {
        int i = base + tid;
        int v = (i < N_NODES) ? deg[i] : 0;
        int incl = wave_incl_scan(v, lane);
        if (lane == 63) wsum[w] = incl;
        __syncthreads();
        if (w == 0) {
            int x = (lane < 16) ? wsum[lane] : 0;
            int xs = wave_incl_scan(x, lane);
            if (lane == 15) chunk_total = xs;
            if (lane < 16) wsum[lane] = xs - x;   // exclusive wave offsets
        }
        __syncthreads();
        int excl = carry_s + wsum[w] + incl - v;
        if (i < N_NODES) { cursor[i] = excl; offs[i] = excl; }
        __syncthreads();                           // all carry_s reads done
        if (tid == 0) carry_s += chunk_total;
        __syncthreads();
    }
}

// ---------------------------------------------------------------------------
// scatter edges into row-sorted order (order within a bucket is arbitrary)
// ---------------------------------------------------------------------------
__global__ void scatter_edges(const int* __restrict__ row, const int* __restrict__ col,
                              int* __restrict__ cursor, int* __restrict__ perm,
                              int* __restrict__ row_s, int* __restrict__ col_s) {
    int e = blockIdx.x * 256 + threadIdx.x;
    if (e >= N_EDGES) return;
    int r = row[e];
    int pos = atomicAdd(&cursor[r], 1);
    perm[pos] = e;
    row_s[pos] = r;
    col_s[pos] = col[e];
}

// ---------------------------------------------------------------------------
// GEMM: PQ[n, 0:512] = h @ W1[0:128,:] + b1 (bias folded into P half)
//       PQ[n, 512:1024] = h @ W1[128:256,:]
// M=20000, N=1024, K=128. 128x128 tile, BK=16, 256 threads, 8x8 micro-tile.
// Inner product uses v_pk_fma_f32 (v2f): 32 packed FMA per kk instead of 64
// scalar — VALU *issue slots* are the f32 ceiling (m07: scalar fma = 103 TF).
// ---------------------------------------------------------------------------
#define TM 128
#define TN 128
#define BK 16
#define NTILES (EMB / BK)   // 8

__global__ __launch_bounds__(256) void gemm_pq(
    const float* __restrict__ h, const float* __restrict__ W1,
    const float* __restrict__ b1, float* __restrict__ PQ)
{
    __shared__ float As[BK][TM + 4];   // transposed A tile, stride 132
    __shared__ float Bs[BK][TN];

    const int tid = threadIdx.x;
    const int nt  = blockIdx.x;           // 0..7: col tile of 128 over 1024
    const int mt  = blockIdx.y;           // 0..156
    const int m_base = mt * TM;

    // A staging: 128 rows x 16 k = 512 float4 -> 2 consecutive f4 per thread
    const int a_m = tid >> 1;             // 0..127
    const int a_k = (tid & 1) << 3;       // 0 or 8
    const int  row_a = m_base + a_m;
    const bool a_ok  = row_a < N_NODES;
    const float* __restrict__ hrow = h + (size_t)row_a * EMB + a_k;

    // B staging: 16 rows x 128 cols = 512 float4 -> 2 per thread (col, col+64)
    const int b_k = tid >> 4;             // 0..15
    const int b_n = (tid & 15) << 2;      // 0..60
    const int w_row_off = (nt < 4) ? 0 : 128;       // P half vs Q half of W1
    const int w_col     = (nt & 3) * TN + b_n;
    const float* __restrict__ wrow = W1 + (size_t)(w_row_off + b_k) * HID + w_col;

    // compute mapping: 16x16 threads, rows {cm.., cm+64..}, cols {cn.., cn+64..}
    const int ty = tid >> 4, tx = tid & 15;
    const int cm = ty << 2, cn = tx << 2;

    v2f acc[8][4] = {};   // rows: i<4 -> cm+i, i>=4 -> cm+64+i-4
                          // col pairs: 0:(cn,cn+1) 1:(cn+2,cn+3) 2:(cn+64,65) 3:(cn+66,67)

    float4 pa0, pa1, pb0, pb1;
    {
        pa0 = make_float4(0.f,0.f,0.f,0.f); pa1 = pa0;
        if (a_ok) { pa0 = *(const float4*)(hrow); pa1 = *(const float4*)(hrow + 4); }
        pb0 = *(const float4*)(wrow);
        pb1 = *(const float4*)(wrow + 64);
    }

    for (int t = 0; t < NTILES; ++t) {
        As[a_k + 0][a_m] = pa0.x;
        As[a_k + 1][a_m] = pa0.y;
        As[a_k + 2][a_m] = pa0.z;
        As[a_k + 3][a_m] = pa0.w;
        As[a_k + 4][a_m] = pa1.x;
        As[a_k + 5][a_m] = pa1.y;
        As[a_k + 6][a_m] = pa1.z;
        As[a_k + 7][a_m] = pa1.w;
        *(float4*)&Bs[b_k][b_n]      = pb0;
        *(float4*)&Bs[b_k][b_n + 64] = pb1;
        __syncthreads();

        if (t + 1 < NTILES) {
            const int k0 = (t + 1) * BK;
            pa0 = make_float4(0.f,0.f,0.f,0.f); pa1 = pa0;
            if (a_ok) { pa0 = *(const float4*)(hrow + k0); pa1 = *(const float4*)(hrow + k0 + 4); }
            pb0 = *(const float4*)(wrow + (size_t)k0 * HID);
            pb1 = *(const float4*)(wrow + (size_t)k0 * HID + 64);
        }

#pragma unroll
        for (int kk = 0; kk < BK; ++kk) {
            float a[8];
            v2f b[4];
            *(float4*)&a[0] = *(const float4*)&As[kk][cm];
            *(float4*)&a[4] = *(const float4*)&As[kk][cm + 64];
            float4 b03 = *(const float4*)&Bs[kk][cn];
            float4 b47 = *(const float4*)&Bs[kk][cn + 64];
            b[0] = (v2f){b03.x, b03.y};
            b[1] = (v2f){b03.z, b03.w};
            b[2] = (v2f){b47.x, b47.y};
            b[3] = (v2f){b47.z, b47.w};
#pragma unroll
            for (int i = 0; i < 8; ++i) {
                v2f ai = (v2f){a[i], a[i]};
#pragma unroll
                for (int j = 0; j < 4; ++j)
                    acc[i][j] = V2FMA(ai, b[j], acc[i][j]);
            }
        }
        __syncthreads();
    }

    const int col_base = nt * TN;

    // bias fold: P half only (global cols < 512)
    v2f bias[4] = {{0.f,0.f},{0.f,0.f},{0.f,0.f},{0.f,0.f}};
    if (nt < 4) {
        float4 bv0 = *(const float4*)(b1 + col_base + cn);
        float4 bv1 = *(const float4*)(b1 + col_base + cn + 64);
        bias[0] = (v2f){bv0.x, bv0.y};
        bias[1] = (v2f){bv0.z, bv0.w};
        bias[2] = (v2f){bv1.x, bv1.y};
        bias[3] = (v2f){bv1.z, bv1.w};
    }

#pragma unroll
    for (int i = 0; i < 8; ++i) {
        const int r = m_base + cm + (i < 4 ? i : 64 + i - 4);
        if (r < N_NODES) {
            float* dst = PQ + (size_t)r * PQ_STRIDE + col_base;
            v2f c0 = acc[i][0] + bias[0], c1 = acc[i][1] + bias[1];
            v2f c2 = acc[i][2] + bias[2], c3 = acc[i][3] + bias[3];
            *(float4*)(dst + cn)      = make_float4(c0.x, c0.y, c1.x, c1.y);
            *(float4*)(dst + cn + 64) = make_float4(c2.x, c2.y, c3.x, c3.y);
        }
    }
}

// ---------------------------------------------------------------------------
// Fused edge phase. Block owns 16 consecutive rows (complete softmax
// segments). Phase 1: wave-per-edge MLP, unrolled x2 so two Q-row gathers
// are in flight; row id comes from row_s (broadcast load — no serial search).
// Phase 2: wave-per-row softmax + relaxed bernoulli + outputs.
// ---------------------------------------------------------------------------
__global__ __launch_bounds__(256) void fused_edge(
    const float* __restrict__ PQ,
    const float* __restrict__ W2, const float* __restrict__ b2,
    const int* __restrict__ row_s, const int* __restrict__ col_s,
    const int* __restrict__ perm, const int* __restrict__ offs,
    const float* __restrict__ u, const int* __restrict__ edge_mask,
    const int* __restrict__ hierarchy,
    float* __restrict__ scores, float* __restrict__ out_y,
    float* __restrict__ out_mask, float* __restrict__ out_causal,
    float* __restrict__ out_spu)
{
    __shared__ float sc_lds[SC_CAP];

    const int r0 = blockIdx.x * ROWS_PER_BLOCK;
    const int r1 = (r0 + ROWS_PER_BLOCK < N_NODES) ? r0 + ROWS_PER_BLOCK : N_NODES;
    const int e0 = offs[r0];
    const int e1 = offs[r1];
    const int tid = threadIdx.x, lane = tid & 63, w = tid >> 6;
    const int j0 = lane << 2;

    // loop-invariant: W2 fragment + bias
    const float4 w0 = *(const float4*)(W2 + j0);
    const float4 w1 = *(const float4*)(W2 + 256 + j0);
    const float bias2 = b2[0];

    // ---- phase 1: scores, two edges per wave-iteration ----
    for (int i0 = e0 + (w << 1); i0 < e1; i0 += 8) {
        const int  iA   = i0;
        const bool hasB = (i0 + 1) < e1;
        const int  iB   = hasB ? i0 + 1 : i0;

        const int rA = row_s[iA], cA = col_s[iA];
        const int rB = row_s[iB], cB = col_s[iB];
        const float* __restrict__ pA = PQ + (size_t)rA * PQ_STRIDE;
        const float* __restrict__ qA = PQ + (size_t)cA * PQ_STRIDE + HID;
        const float* __restrict__ pB = PQ + (size_t)rB * PQ_STRIDE;
        const float* __restrict__ qB = PQ + (size_t)cB * PQ_STRIDE + HID;

        float4 pA0 = *(const float4*)(pA + j0);
        float4 pA1 = *(const float4*)(pA + 256 + j0);
        float4 qA0 = *(const float4*)(qA + j0);
        float4 qA1 = *(const float4*)(qA + 256 + j0);
        float4 pB0 = *(const float4*)(pB + j0);
        float4 pB1 = *(const float4*)(pB + 256 + j0);
        float4 qB0 = *(const float4*)(qB + j0);
        float4 qB1 = *(const float4*)(qB + 256 + j0);

        float sA = 0.0f, sB = 0.0f;
        sA = fmaf(fmaxf(pA0.x + qA0.x, 0.0f), w0.x, sA);
        sA = fmaf(fmaxf(pA0.y + qA0.y, 0.0f), w0.y, sA);
        sA = fmaf(fmaxf(pA0.z + qA0.z, 0.0f), w0.z, sA);
        sA = fmaf(fmaxf(pA0.w + qA0.w, 0.0f), w0.w, sA);
        sA = fmaf(fmaxf(pA1.x + qA1.x, 0.0f), w1.x, sA);
        sA = fmaf(fmaxf(pA1.y + qA1.y, 0.0f), w1.y, sA);
        sA = fmaf(fmaxf(pA1.z + qA1.z, 0.0f), w1.z, sA);
        sA = fmaf(fmaxf(pA1.w + qA1.w, 0.0f), w1.w, sA);
        sB = fmaf(fmaxf(pB0.x + qB0.x, 0.0f), w0.x, sB);
        sB = fmaf(fmaxf(pB0.y + qB0.y, 0.0f), w0.y, sB);
        sB = fmaf(fmaxf(pB0.z + qB0.z, 0.0f), w0.z, sB);
        sB = fmaf(fmaxf(pB0.w + qB0.w, 0.0f), w0.w, sB);
        sB = fmaf(fmaxf(pB1.x + qB1.x, 0.0f), w1.x, sB);
        sB = fmaf(fmaxf(pB1.y + qB1.y, 0.0f), w1.y, sB);
        sB = fmaf(fmaxf(pB1.z + qB1.z, 0.0f), w1.z, sB);
        sB = fmaf(fmaxf(pB1.w + qB1.w, 0.0f), w1.w, sB);

#pragma unroll
        for (int off = 32; off > 0; off >>= 1) {
            sA += __shfl_down(sA, off, 64);
            sB += __shfl_down(sB, off, 64);
        }

        if (lane == 0) {
            float scA = sA + bias2;
            scores[perm[iA]] = scA;
            sc_lds[iA - e0] = scA;          // iA-e0 < SC_CAP by construction below
            if (hasB) {
                float scB = sB + bias2;
                scores[perm[iB]] = scB;
                int li = iB - e0;
                if (li < SC_CAP) sc_lds[li] = scB;
            }
        }
    }
    __syncthreads();

    // ---- phase 2: wave per row ----
    const int hv = hierarchy[0];
    for (int r = r0 + w; r < r1; r += 4) {
        const int es = offs[r], ee = offs[r + 1];
        const int d = ee - es;
        if (d == 0) continue;

        float m = -INFINITY;
        for (int j = lane; j < d; j += 64) {
            int li = es - e0 + j;
            float s = (li < SC_CAP) ? sc_lds[li] : scores[perm[es + j]];
            m = fmaxf(m, s);
        }
#pragma unroll
        for (int off = 32; off > 0; off >>= 1)
            m = fmaxf(m, __shfl_down(m, off, 64));
        m = __shfl(m, 0, 64);

        float ssum = 0.0f;
        for (int j = lane; j < d; j += 64) {
            int li = es - e0 + j;
            float s = (li < SC_CAP) ? sc_lds[li] : scores[perm[es + j]];
            ssum += expf(s - m);
        }
#pragma unroll
        for (int off = 32; off > 0; off >>= 1)
            ssum += __shfl_down(ssum, off, 64);
        ssum = __shfl(ssum, 0, 64);

        for (int j = lane; j < d; j += 64) {
            int li = es - e0 + j;
            float s = (li < SC_CAP) ? sc_lds[li] : scores[perm[es + j]];
            float p = expf(s - m) / ssum;
            float logits = logf(p) - log1pf(-p);   // +inf when p==1 (d==1)
            int oe = perm[es + j];
            float uu = u[oe];
            float L = logf(uu) - log1pf(-uu);
            float y = 1.0f / (1.0f + expf(-(logits + L)));
            bool hard = y > 0.5f;                  // ST forward value == y_hard
            int mm = hard ? (hv + 1) : edge_mask[oe];
            out_y[oe]      = hard ? 1.0f : 0.0f;
            out_mask[oe]   = (float)mm;
            out_causal[oe] = (mm > 0)   ?  s : 0.0f;
            out_spu[oe]    = (mm == -1) ? -s : 0.0f;
        }
    }
}

// ---------------------------------------------------------------------------
extern "C" void kernel_launch(void* const* d_in, const int* in_sizes, int n_in,
                              void* d_out, int out_size, void* d_ws, size_t ws_size,
                              hipStream_t stream) {
    const float* h_ptr = (const float*)d_in[0];
    const float* W1    = (const float*)d_in[1];
    const float* b1    = (const float*)d_in[2];
    const float* W2    = (const float*)d_in[3];
    const float* b2    = (const float*)d_in[4];
    const float* u     = (const float*)d_in[5];
    const int*   row   = (const int*)d_in[6];
    const int*   col   = (const int*)d_in[7];
    const int*   emask = (const int*)d_in[8];
    const int*   hier  = (const int*)d_in[9];

    float* out        = (float*)d_out;
    float* scores     = out;                        // [E]
    float* out_y      = out + (size_t)N_EDGES;      // [E]
    float* out_mask   = out + 2 * (size_t)N_EDGES;  // [E]
    float* out_causal = out + 3 * (size_t)N_EDGES;  // [E]
    float* out_spu    = out + 4 * (size_t)N_EDGES;  // [E]

    // workspace layout (4B units), PQ first for 16B alignment:
    // PQ[20000*1024] deg[20000] cursor[20000] offs[20001] perm[E] row_s[E] col_s[E]
    float* PQ     = (float*)d_ws;
    int*   deg    = (int*)(PQ + (size_t)N_NODES * PQ_STRIDE);
    int*   cursor = deg + N_NODES;
    int*   offs   = cursor + N_NODES;
    int*   perm   = offs + N_NODES + 1;
    int*   row_s  = perm + N_EDGES;
    int*   col_s  = row_s + N_EDGES;

    hipLaunchKernelGGL(init_deg, dim3((N_NODES + 255) / 256), dim3(256), 0, stream,
                       deg, offs);

    hipLaunchKernelGGL(histogram_rows, dim3((N_EDGES + 255) / 256), dim3(256), 0, stream,
                       row, deg);

    hipLaunchKernelGGL(scan_offsets, dim3(1), dim3(1024), 0, stream, deg, cursor, offs);

    hipLaunchKernelGGL(scatter_edges, dim3((N_EDGES + 255) / 256), dim3(256), 0, stream,
                       row, col, cursor, perm, row_s, col_s);

    dim3 ggrid(PQ_STRIDE / TN, (N_NODES + TM - 1) / TM);  // 8 x 157
    hipLaunchKernelGGL(gemm_pq, ggrid, dim3(256), 0, stream, h_ptr, W1, b1, PQ);

    hipLaunchKernelGGL(fused_edge, dim3((N_NODES + ROWS_PER_BLOCK - 1) / ROWS_PER_BLOCK),
                       dim3(256), 0, stream,
                       PQ, W2, b2, row_s, col_s, perm, offs, u, emask, hier,
                       scores, out_y, out_mask, out_causal, out_spu);
}

// Round 5
// 312.629 us; speedup vs baseline: 1.1718x; 1.0347x over previous
//
#include <hip/hip_runtime.h>
#include <math.h>

#define N_NODES 20000
#define N_EDGES 320000
#define EMB 128
#define HID 512          // 4*EMB
#define PQ_STRIDE 1024   // P (512, bias-folded) + Q (512) per node
#define ROWS_PER_BLOCK 16
#define SC_CAP 2048      // LDS score cache per block (spill path for skew)
#define NCHUNK ((N_NODES + 1023) / 1024)   // 20

typedef float v2f __attribute__((ext_vector_type(2)));

#if defined(__has_builtin)
#if __has_builtin(__builtin_elementwise_fma)
#define V2FMA(a, b, c) __builtin_elementwise_fma((a), (b), (c))
#else
#define V2FMA(a, b, c) ((a) * (b) + (c))
#endif
#else
#define V2FMA(a, b, c) ((a) * (b) + (c))
#endif

// ---------------------------------------------------------------------------
__global__ void init_deg(int* __restrict__ deg, int* __restrict__ offs) {
    int i = blockIdx.x * 256 + threadIdx.x;
    if (i < N_NODES) deg[i] = 0;
    if (i == 0) offs[N_NODES] = N_EDGES;
}

__global__ void histogram_rows(const int* __restrict__ row, int* __restrict__ deg) {
    int e = blockIdx.x * 256 + threadIdx.x;
    if (e < N_EDGES) atomicAdd(&deg[row[e]], 1);
}

// ---------------------------------------------------------------------------
// hierarchical exclusive scan over deg (replaces the serial single-block scan:
// that kernel was ~20 chunk-iterations of load-latency + barriers on ONE CU)
// ---------------------------------------------------------------------------
__device__ __forceinline__ int wave_incl_scan(int v, int lane) {
#pragma unroll
    for (int off = 1; off < 64; off <<= 1) {
        int t = __shfl_up(v, off, 64);
        if (lane >= off) v += t;
    }
    return v;
}

__global__ __launch_bounds__(1024) void scan_part(const int* __restrict__ deg,
                                                  int* __restrict__ part,
                                                  int* __restrict__ totals) {
    __shared__ int wsum[16];
    const int tid = threadIdx.x, lane = tid & 63, w = tid >> 6;
    const int i = blockIdx.x * 1024 + tid;
    int v = (i < N_NODES) ? deg[i] : 0;
    int incl = wave_incl_scan(v, lane);
    if (lane == 63) wsum[w] = incl;
    __syncthreads();
    if (w == 0) {
        int x = (lane < 16) ? wsum[lane] : 0;
        int xs = wave_incl_scan(x, lane);
        if (lane < 16) wsum[lane] = xs - x;       // exclusive wave offsets
        if (lane == 15) totals[blockIdx.x] = xs;  // chunk total
    }
    __syncthreads();
    if (i < N_NODES) part[i] = wsum[w] + incl - v;
}

__global__ void scan_carry(const int* __restrict__ totals, int* __restrict__ carry) {
    const int lane = threadIdx.x;   // one wave
    int v = (lane < NCHUNK) ? totals[lane] : 0;
    int incl = wave_incl_scan(v, lane);
    if (lane < NCHUNK) carry[lane] = incl - v;
}

__global__ __launch_bounds__(1024) void scan_apply(const int* __restrict__ part,
                                                   const int* __restrict__ carry,
                                                   int* __restrict__ cursor,
                                                   int* __restrict__ offs) {
    const int i = blockIdx.x * 1024 + threadIdx.x;
    if (i < N_NODES) {
        int o = part[i] + carry[blockIdx.x];
        cursor[i] = o;
        offs[i] = o;
    }
}

// ---------------------------------------------------------------------------
__global__ void scatter_edges(const int* __restrict__ row, const int* __restrict__ col,
                              int* __restrict__ cursor, int* __restrict__ perm,
                              int* __restrict__ row_s, int* __restrict__ col_s) {
    int e = blockIdx.x * 256 + threadIdx.x;
    if (e >= N_EDGES) return;
    int r = row[e];
    int pos = atomicAdd(&cursor[r], 1);
    perm[pos] = e;
    row_s[pos] = r;
    col_s[pos] = col[e];
}

// ---------------------------------------------------------------------------
// GEMM: PQ[:,0:512] = h@W1[0:128,:] + b1 ; PQ[:,512:1024] = h@W1[128:256,:]
// 128x128 tile, BK=16, 512 threads (8 waves), 4x8 micro-tile (v_pk_fma_f32),
// LDS DOUBLE-BUFFER -> one barrier per K-tile (8 total). 33 KB LDS, small
// per-thread state (~32 acc VGPR) for high waves/CU.
// ---------------------------------------------------------------------------
#define TM 128
#define TN 128
#define BK 16
#define NTILES (EMB / BK)   // 8

__global__ __launch_bounds__(512) void gemm_pq(
    const float* __restrict__ h, const float* __restrict__ W1,
    const float* __restrict__ b1, float* __restrict__ PQ)
{
    __shared__ float As[2][BK][TM + 4];   // transposed A, stride 132
    __shared__ float Bs[2][BK][TN];

    const int tid = threadIdx.x;
    const int nt  = blockIdx.x;           // 0..7
    const int mt  = blockIdx.y;           // 0..156
    const int m_base = mt * TM;

    // A staging: 2048 floats = 512 float4 -> 1 per thread
    const int a_m = tid >> 2;             // 0..127
    const int a_k = (tid & 3) << 2;       // 0,4,8,12
    const int  row_a = m_base + a_m;
    const bool a_ok  = row_a < N_NODES;
    const float* __restrict__ hrow = h + (size_t)row_a * EMB + a_k;

    // B staging: 2048 floats -> 1 float4 per thread
    const int b_k = tid >> 5;             // 0..15
    const int b_n = (tid & 31) << 2;      // 0..124
    const int w_row_off = (nt < 4) ? 0 : 128;
    const int w_col     = (nt & 3) * TN + b_n;
    const float* __restrict__ wrow = W1 + (size_t)(w_row_off + b_k) * HID + w_col;

    // compute: 32x16 threads, 4 rows x 8 cols (pairs at cn and cn+64)
    const int ty = tid >> 4, tx = tid & 15;
    const int cm = ty << 2, cn = tx << 2;

    v2f acc[4][4] = {};   // [row i][pair j: (cn,cn+1)(cn+2,cn+3)(cn+64,65)(cn+66,67)]

    float4 pa, pb;
    pa = make_float4(0.f, 0.f, 0.f, 0.f);
    if (a_ok) pa = *(const float4*)(hrow);
    pb = *(const float4*)(wrow);
    As[0][a_k + 0][a_m] = pa.x;
    As[0][a_k + 1][a_m] = pa.y;
    As[0][a_k + 2][a_m] = pa.z;
    As[0][a_k + 3][a_m] = pa.w;
    *(float4*)&Bs[0][b_k][b_n] = pb;
    __syncthreads();

    for (int t = 0; t < NTILES; ++t) {
        const int cur = t & 1;
        if (t + 1 < NTILES) {
            const int k0 = (t + 1) * BK;
            pa = make_float4(0.f, 0.f, 0.f, 0.f);
            if (a_ok) pa = *(const float4*)(hrow + k0);
            pb = *(const float4*)(wrow + (size_t)k0 * HID);
        }

#pragma unroll
        for (int kk = 0; kk < BK; ++kk) {
            float4 a4 = *(const float4*)&As[cur][kk][cm];
            float4 b0 = *(const float4*)&Bs[cur][kk][cn];
            float4 b1v = *(const float4*)&Bs[cur][kk][cn + 64];
            v2f bp[4] = {(v2f){b0.x, b0.y}, (v2f){b0.z, b0.w},
                         (v2f){b1v.x, b1v.y}, (v2f){b1v.z, b1v.w}};
            float a[4] = {a4.x, a4.y, a4.z, a4.w};
#pragma unroll
            for (int i = 0; i < 4; ++i) {
                v2f ai = (v2f){a[i], a[i]};
#pragma unroll
                for (int j = 0; j < 4; ++j)
                    acc[i][j] = V2FMA(ai, bp[j], acc[i][j]);
            }
        }

        if (t + 1 < NTILES) {
            const int nxt = 1 - cur;
            As[nxt][a_k + 0][a_m] = pa.x;
            As[nxt][a_k + 1][a_m] = pa.y;
            As[nxt][a_k + 2][a_m] = pa.z;
            As[nxt][a_k + 3][a_m] = pa.w;
            *(float4*)&Bs[nxt][b_k][b_n] = pb;
            __syncthreads();
        }
    }

    const int col_base = nt * TN;
    v2f bias[4] = {{0.f,0.f},{0.f,0.f},{0.f,0.f},{0.f,0.f}};
    if (nt < 4) {  // bias fold: P half only
        float4 bv0 = *(const float4*)(b1 + col_base + cn);
        float4 bv1 = *(const float4*)(b1 + col_base + cn + 64);
        bias[0] = (v2f){bv0.x, bv0.y};
        bias[1] = (v2f){bv0.z, bv0.w};
        bias[2] = (v2f){bv1.x, bv1.y};
        bias[3] = (v2f){bv1.z, bv1.w};
    }

#pragma unroll
    for (int i = 0; i < 4; ++i) {
        const int r = m_base + cm + i;
        if (r < N_NODES) {
            float* dst = PQ + (size_t)r * PQ_STRIDE + col_base;
            v2f c0 = acc[i][0] + bias[0], c1 = acc[i][1] + bias[1];
            v2f c2 = acc[i][2] + bias[2], c3 = acc[i][3] + bias[3];
            *(float4*)(dst + cn)      = make_float4(c0.x, c0.y, c1.x, c1.y);
            *(float4*)(dst + cn + 64) = make_float4(c2.x, c2.y, c3.x, c3.y);
        }
    }
}

// ---------------------------------------------------------------------------
// Fused edge phase. Block owns 16 consecutive rows (complete segments).
// Phase 1: wave-per-edge MLP, UNROLL x4 (16 float4 gathers in flight).
// Phase 2: wave-per-row softmax + relaxed bernoulli + outputs.
// ---------------------------------------------------------------------------
__global__ __launch_bounds__(256) void fused_edge(
    const float* __restrict__ PQ,
    const float* __restrict__ W2, const float* __restrict__ b2,
    const int* __restrict__ row_s, const int* __restrict__ col_s,
    const int* __restrict__ perm, const int* __restrict__ offs,
    const float* __restrict__ u, const int* __restrict__ edge_mask,
    const int* __restrict__ hierarchy,
    float* __restrict__ scores, float* __restrict__ out_y,
    float* __restrict__ out_mask, float* __restrict__ out_causal,
    float* __restrict__ out_spu)
{
    __shared__ float sc_lds[SC_CAP];

    const int r0 = blockIdx.x * ROWS_PER_BLOCK;
    const int r1 = (r0 + ROWS_PER_BLOCK < N_NODES) ? r0 + ROWS_PER_BLOCK : N_NODES;
    const int e0 = offs[r0];
    const int e1 = offs[r1];
    const int tid = threadIdx.x, lane = tid & 63, w = tid >> 6;
    const int j0 = lane << 2;

    const float4 w0 = *(const float4*)(W2 + j0);
    const float4 w1 = *(const float4*)(W2 + 256 + j0);
    const float bias2 = b2[0];

    // ---- phase 1: scores, four edges per wave-iteration ----
    for (int i0 = e0 + (w << 2); i0 < e1; i0 += 16) {
        int  idx[4];
        bool ok[4];
#pragma unroll
        for (int k = 0; k < 4; ++k) {
            ok[k]  = (i0 + k) < e1;
            idx[k] = ok[k] ? (i0 + k) : i0;
        }

        const float* p[4];
        const float* q[4];
#pragma unroll
        for (int k = 0; k < 4; ++k) {
            int r = row_s[idx[k]], c = col_s[idx[k]];
            p[k] = PQ + (size_t)r * PQ_STRIDE;
            q[k] = PQ + (size_t)c * PQ_STRIDE + HID;
        }

        float4 P0[4], P1[4], Q0[4], Q1[4];
#pragma unroll
        for (int k = 0; k < 4; ++k) {
            P0[k] = *(const float4*)(p[k] + j0);
            P1[k] = *(const float4*)(p[k] + 256 + j0);
            Q0[k] = *(const float4*)(q[k] + j0);
            Q1[k] = *(const float4*)(q[k] + 256 + j0);
        }

        float s[4];
#pragma unroll
        for (int k = 0; k < 4; ++k) {
            float v = 0.0f;
            v = fmaf(fmaxf(P0[k].x + Q0[k].x, 0.0f), w0.x, v);
            v = fmaf(fmaxf(P0[k].y + Q0[k].y, 0.0f), w0.y, v);
            v = fmaf(fmaxf(P0[k].z + Q0[k].z, 0.0f), w0.z, v);
            v = fmaf(fmaxf(P0[k].w + Q0[k].w, 0.0f), w0.w, v);
            v = fmaf(fmaxf(P1[k].x + Q1[k].x, 0.0f), w1.x, v);
            v = fmaf(fmaxf(P1[k].y + Q1[k].y, 0.0f), w1.y, v);
            v = fmaf(fmaxf(P1[k].z + Q1[k].z, 0.0f), w1.z, v);
            v = fmaf(fmaxf(P1[k].w + Q1[k].w, 0.0f), w1.w, v);
            s[k] = v;
        }

#pragma unroll
        for (int off = 32; off > 0; off >>= 1) {
#pragma unroll
            for (int k = 0; k < 4; ++k)
                s[k] += __shfl_down(s[k], off, 64);
        }

        if (lane == 0) {
#pragma unroll
            for (int k = 0; k < 4; ++k) {
                if (ok[k]) {
                    float sc = s[k] + bias2;
                    scores[perm[idx[k]]] = sc;
                    int li = idx[k] - e0;
                    if (li < SC_CAP) sc_lds[li] = sc;
                }
            }
        }
    }
    __syncthreads();

    // ---- phase 2: wave per row ----
    const int hv = hierarchy[0];
    for (int r = r0 + w; r < r1; r += 4) {
        const int es = offs[r], ee = offs[r + 1];
        const int d = ee - es;
        if (d == 0) continue;

        float m = -INFINITY;
        for (int j = lane; j < d; j += 64) {
            int li = es - e0 + j;
            float s = (li < SC_CAP) ? sc_lds[li] : scores[perm[es + j]];
            m = fmaxf(m, s);
        }
#pragma unroll
        for (int off = 32; off > 0; off >>= 1)
            m = fmaxf(m, __shfl_down(m, off, 64));
        m = __shfl(m, 0, 64);

        float ssum = 0.0f;
        for (int j = lane; j < d; j += 64) {
            int li = es - e0 + j;
            float s = (li < SC_CAP) ? sc_lds[li] : scores[perm[es + j]];
            ssum += expf(s - m);
        }
#pragma unroll
        for (int off = 32; off > 0; off >>= 1)
            ssum += __shfl_down(ssum, off, 64);
        ssum = __shfl(ssum, 0, 64);

        for (int j = lane; j < d; j += 64) {
            int li = es - e0 + j;
            float s = (li < SC_CAP) ? sc_lds[li] : scores[perm[es + j]];
            float p = expf(s - m) / ssum;
            float logits = logf(p) - log1pf(-p);   // +inf when p==1 (d==1)
            int oe = perm[es + j];
            float uu = u[oe];
            float L = logf(uu) - log1pf(-uu);
            float y = 1.0f / (1.0f + expf(-(logits + L)));
            bool hard = y > 0.5f;                  // ST forward value == y_hard
            int mm = hard ? (hv + 1) : edge_mask[oe];
            out_y[oe]      = hard ? 1.0f : 0.0f;
            out_mask[oe]   = (float)mm;
            out_causal[oe] = (mm > 0)   ?  s : 0.0f;
            out_spu[oe]    = (mm == -1) ? -s : 0.0f;
        }
    }
}

// ---------------------------------------------------------------------------
extern "C" void kernel_launch(void* const* d_in, const int* in_sizes, int n_in,
                              void* d_out, int out_size, void* d_ws, size_t ws_size,
                              hipStream_t stream) {
    const float* h_ptr = (const float*)d_in[0];
    const float* W1    = (const float*)d_in[1];
    const float* b1    = (const float*)d_in[2];
    const float* W2    = (const float*)d_in[3];
    const float* b2    = (const float*)d_in[4];
    const float* u     = (const float*)d_in[5];
    const int*   row   = (const int*)d_in[6];
    const int*   col   = (const int*)d_in[7];
    const int*   emask = (const int*)d_in[8];
    const int*   hier  = (const int*)d_in[9];

    float* out        = (float*)d_out;
    float* scores     = out;                        // [E]
    float* out_y      = out + (size_t)N_EDGES;      // [E]
    float* out_mask   = out + 2 * (size_t)N_EDGES;  // [E]
    float* out_causal = out + 3 * (size_t)N_EDGES;  // [E]
    float* out_spu    = out + 4 * (size_t)N_EDGES;  // [E]

    // workspace (4B units), PQ first for 16B alignment:
    float* PQ     = (float*)d_ws;
    int*   deg    = (int*)(PQ + (size_t)N_NODES * PQ_STRIDE);
    int*   cursor = deg + N_NODES;
    int*   offs   = cursor + N_NODES;               // [N_NODES+1]
    int*   part   = offs + N_NODES + 1;
    int*   totals = part + N_NODES;                 // [NCHUNK]
    int*   carry  = totals + NCHUNK;                // [NCHUNK]
    int*   perm   = carry + NCHUNK;
    int*   row_s  = perm + N_EDGES;
    int*   col_s  = row_s + N_EDGES;

    hipLaunchKernelGGL(init_deg, dim3((N_NODES + 255) / 256), dim3(256), 0, stream,
                       deg, offs);
    hipLaunchKernelGGL(histogram_rows, dim3((N_EDGES + 255) / 256), dim3(256), 0, stream,
                       row, deg);
    hipLaunchKernelGGL(scan_part, dim3(NCHUNK), dim3(1024), 0, stream, deg, part, totals);
    hipLaunchKernelGGL(scan_carry, dim3(1), dim3(64), 0, stream, totals, carry);
    hipLaunchKernelGGL(scan_apply, dim3(NCHUNK), dim3(1024), 0, stream,
                       part, carry, cursor, offs);
    hipLaunchKernelGGL(scatter_edges, dim3((N_EDGES + 255) / 256), dim3(256), 0, stream,
                       row, col, cursor, perm, row_s, col_s);

    dim3 ggrid(PQ_STRIDE / TN, (N_NODES + TM - 1) / TM);  // 8 x 157
    hipLaunchKernelGGL(gemm_pq, ggrid, dim3(512), 0, stream, h_ptr, W1, b1, PQ);

    hipLaunchKernelGGL(fused_edge, dim3((N_NODES + ROWS_PER_BLOCK - 1) / ROWS_PER_BLOCK),
                       dim3(256), 0, stream,
                       PQ, W2, b2, row_s, col_s, perm, offs, u, emask, hier,
                       scores, out_y, out_mask, out_causal, out_spu);
}